// Round 8
// baseline (117.998 us; speedup 1.0000x reference)
//
#include <hip/hip_runtime.h>
#include <math.h>

#define DEV static __device__ __forceinline__

constexpr int SS = 12;
constexpr int NN = 207;
constexpr int NCIRC = 64 * NN;          // 13248 circuits
constexpr int NPAIR = NCIRC / 2;        // 6624 waves; circuit A = lanes 0-31, B = lanes 32-63
// pair (g, g+6624): 6624 = 32*207 -> same node -> shared adjacency mask,
// conv matrices, w1/w2 rows; both circuits share ONE instruction stream.

// Layout: 32 lanes/circuit, 8 amps/lane (v2f a[8], re/im packed).
// Amp index bits 0,1,2 = in-lane "K slots"; amp bits 3..7 = lane bits 0..4
// ("L slots"); lane bit 5 = circuit selector. Initially qubit q sits at amp
// bit (7-q): K = {q7@k0, q6@k1, q5@k2}, L: l0=q4,l1=q3,l2=q2,l3=q1,l4=q0.
// Conv pair = real 4x4 matrix (prep_kernel) on two K bits, spectator K bit
// doubles the groups. 10 swaps total (5/layer) + 3 pool swaps.
// Hard rules (R2/R3): state arrays use ONLY compile-time indices; runtime
// permutes go through wave-uniform switch; static-mask __shfl_xor everywhere.

typedef float v2f __attribute__((ext_vector_type(2)));
typedef float v4f __attribute__((ext_vector_type(4)));

DEV v2f splat2(float x) { v2f r; r.x = x; r.y = x; return r; }
DEV v2f vfma(float m, v2f a, v2f acc) { return __builtin_elementwise_fma(splat2(m), a, acc); }
DEV v2f vmul(float m, v2f a) { return splat2(m) * a; }
template<int M> DEV float sxc(float v) { return __shfl_xor(v, M, 64); }
template<int M> DEV v2f sx2(v2f v) { v2f r; r.x = sxc<M>(v.x); r.y = sxc<M>(v.y); return r; }
DEV float bperm(int addr, float v) {
    return __int_as_float(__builtin_amdgcn_ds_bpermute(addr, __float_as_int(v)));
}

// real 4x4 conv matrix P (row r=2h+l) on K bits BH(hi=qubit i), BL(lo=i+1)
template<int BH, int BL>
DEV void convm(v2f a[8], const float* __restrict__ P) {
    constexpr int mh = 1 << BH, ml = 1 << BL;
#pragma unroll
    for (int j = 0; j < 8; j++) {
        if (j & (mh | ml)) continue;
        v2f b00 = a[j], b01 = a[j + ml], b10 = a[j + mh], b11 = a[j + mh + ml];
        a[j]         = vfma(P[0],  b00, vfma(P[1],  b01, vfma(P[2],  b10, vmul(P[3],  b11))));
        a[j + ml]    = vfma(P[4],  b00, vfma(P[5],  b01, vfma(P[6],  b10, vmul(P[7],  b11))));
        a[j + mh]    = vfma(P[8],  b00, vfma(P[9],  b01, vfma(P[10], b10, vmul(P[11], b11))));
        a[j + mh+ml] = vfma(P[12], b00, vfma(P[13], b01, vfma(P[14], b10, vmul(P[15], b11))));
    }
}

// half-shuffle swap of K bit KB with lane bit LB (R7-verified pattern)
template<int KB, int LB>
DEV void swkl(v2f a[8], int lane) {
    constexpr int m = 1 << KB, ML = 1 << LB;
    const bool lb = (lane >> LB) & 1;
#pragma unroll
    for (int j = 0; j < 8; j++) {
        if (j & m) continue;
        v2f u = lb ? a[j] : a[j | m];
        v2f v = sx2<ML>(u);
        a[j]     = lb ? v : a[j];
        a[j | m] = lb ? a[j | m] : v;
    }
}

// in-lane RY on K bit KB
template<int KB>
DEV void ry_k(v2f a[8], float c, float s) {
    constexpr int m = 1 << KB;
#pragma unroll
    for (int j = 0; j < 8; j++) {
        if (j & m) continue;
        v2f lo = a[j], hi = a[j | m];
        a[j]     = vfma(c, lo, vmul(-s, hi));
        a[j | m] = vfma(s, lo, vmul(c, hi));
    }
}

// WHT butterfly stage (R7-verified)
template<int MK> DEV float whts(float p, int lane) {
    float t = sxc<MK>(p);
    return (lane & MK) ? (t - p) : (p + t);
}

// ---- prep: fuse conv pair (RYhi,RYlo,CNOT(hi->lo),RYhi,RYlo,CNOT(lo->hi))
// into one real 4x4; basis idx = 2*b_hi + b_lo, hi = qubit i, lo = i+1.
// ws[16n..]: matrix for conv n (execution-schedule order); ws[224..229]:
// pool (c,s) for q0,q2,q4; conv 13 has pool-RY(q6) (lo slot) folded in.
__global__ void prep_kernel(const float* __restrict__ qp, float* __restrict__ ws) {
    const int n = threadIdx.x;
    if (n == 14) {
        float s, c;
        sincosf(0.5f * qp[56], &s, &c); ws[224] = c; ws[225] = s;
        sincosf(0.5f * qp[58], &s, &c); ws[226] = c; ws[227] = s;
        sincosf(0.5f * qp[60], &s, &c); ws[228] = c; ws[229] = s;
    }
    if (n >= 14) return;
    // schedule: L1 (6,7)(4,5)(5,6)(2,3)(3,4)(0,1)(1,2); L2 (0,1)(2,3)(1,2)(4,5)(3,4)(6,7)(5,6)
    const int Jt[14] = {12, 8, 24, 4, 20, 0, 16, 28, 32, 44, 36, 48, 40, 52};
    const int J = Jt[n];
    float cg[4], sg[4];
    for (int i = 0; i < 4; i++) sincosf(0.5f * qp[J + i], &sg[i], &cg[i]);
    float A[16], B[16], M[16];
    {
        float H[2][2] = {{cg[0], -sg[0]}, {sg[0], cg[0]}};
        float L[2][2] = {{cg[1], -sg[1]}, {sg[1], cg[1]}};
        for (int a_ = 0; a_ < 2; a_++) for (int b_ = 0; b_ < 2; b_++)
            for (int p = 0; p < 2; p++) for (int q = 0; q < 2; q++)
                A[(2*a_+b_)*4 + (2*p+q)] = H[a_][p] * L[b_][q];
    }
    for (int j = 0; j < 4; j++) { float t = A[8+j]; A[8+j] = A[12+j]; A[12+j] = t; }  // CNOT hi->lo
    {
        float H[2][2] = {{cg[2], -sg[2]}, {sg[2], cg[2]}};
        float L[2][2] = {{cg[3], -sg[3]}, {sg[3], cg[3]}};
        for (int a_ = 0; a_ < 2; a_++) for (int b_ = 0; b_ < 2; b_++)
            for (int p = 0; p < 2; p++) for (int q = 0; q < 2; q++)
                B[(2*a_+b_)*4 + (2*p+q)] = H[a_][p] * L[b_][q];
    }
    for (int r = 0; r < 4; r++)
        for (int c = 0; c < 4; c++) {
            float acc = 0.0f;
            for (int k = 0; k < 4; k++) acc += B[r*4+k] * A[k*4+c];
            M[r*4+c] = acc;
        }
    for (int j = 0; j < 4; j++) { float t = M[4+j]; M[4+j] = M[12+j]; M[12+j] = t; }  // CNOT lo->hi
    if (n == 13) {          // fold pool RY(q6); q6 = lo slot of conv (5,6)
        float ps, pc;
        sincosf(0.5f * qp[62], &ps, &pc);
        for (int g = 0; g < 4; g += 2)
            for (int j = 0; j < 4; j++) {
                float r0 = M[g*4+j], r1 = M[(g+1)*4+j];
                M[g*4+j]     = pc * r0 - ps * r1;
                M[(g+1)*4+j] = ps * r0 + pc * r1;
            }
    }
    for (int i = 0; i < 16; i++) ws[16*n + i] = M[i];
}

__global__ __launch_bounds__(256) void qcnn_kernel(
    const float* __restrict__ x, const float* __restrict__ adj,
    const float* __restrict__ w_proj, const float* __restrict__ b_proj,
    const float* __restrict__ ws,
    const float* __restrict__ w1, const float* __restrict__ b1,
    const float* __restrict__ w2, const float* __restrict__ b2,
    const float* __restrict__ w3, const float* __restrict__ b3,
    float* __restrict__ out)
{
    const int lane = threadIdx.x & 63;
    const int half = lane >> 5;                  // 0 = circuit A, 1 = circuit B
    const int hl   = lane & 31;
    const int wv   = threadIdx.x >> 6;
    const int gA   = blockIdx.x * 4 + wv;        // grid exact: 1656*4 == 6624
    const int bA   = gA / NN;
    const int node = gA - bA * NN;
    const int bb   = bA + (half << 5);           // circuit B: b += 32, same node

    // ---- angles = x-slice @ w_proj.T + b_proj, clipped to [-pi, pi] ----
    const float* xp = x + ((size_t)bb * SS * NN + node) * 2;
    v2f av[8];
#pragma unroll
    for (int k = 0; k < 8; k++) av[k] = splat2(0.0f);
#pragma unroll
    for (int s = 0; s < SS; s++) {
        const v2f xv = *(const v2f*)(xp + (size_t)s * (NN * 2));
#pragma unroll
        for (int k = 0; k < 8; k++) {
            const v2f wv2 = *(const v2f*)(w_proj + k * 24 + 2 * s);
            av[k] = __builtin_elementwise_fma(xv, wv2, av[k]);
        }
    }
    const float PI_F = 3.14159265358979323846f;
    float ang[8];
#pragma unroll
    for (int k = 0; k < 8; k++)
        ang[k] = fminf(fmaxf(av[k].x + av[k].y + b_proj[k], -PI_F), PI_F);

    // ---- analytic product state (RY layer + RZ phases) ----
    float cc[8], ssn[8];
#pragma unroll
    for (int i = 0; i < 8; i++) __sincosf(0.5f * ang[i], &ssn[i], &cc[i]);
    float A = 1.0f;
#pragma unroll
    for (int i = 0; i < 5; i++)              // qubits 0..4 -> lane bits 4-i
        A *= ((lane >> (4 - i)) & 1) ? ssn[i] : cc[i];
    float phi = 0.0f;
#pragma unroll
    for (int i = 0; i < 4; i++)              // RZ on qubits 0..3 -> lane bits 4..1
        phi += ((lane >> (4 - i)) & 1) ? 0.5f * ang[4 + i] : -0.5f * ang[4 + i];
    float cp, sp;
    __sincosf(phi, &sp, &cp);
    v2f ph; ph.x = cp; ph.y = sp;

    v2f a[8];   // amp bit0=q7, bit1=q6, bit2=q5
#pragma unroll
    for (int k = 0; k < 8; k++) {
        float coef = A * ((k & 4) ? ssn[5] : cc[5])
                       * ((k & 2) ? ssn[6] : cc[6])
                       * ((k & 1) ? ssn[7] : cc[7]);
        a[k] = vmul(coef, ph);
    }

    // ---- adjacency-controlled CNOT chain == one XOR-mask permutation ----
    const int cq = node & 7;
    int M = 0;
#pragma unroll
    for (int t = 0; t < 8; t++) {
        float avv = adj[cq * NN + t];
        if (t != cq && avv > 0.0f) M |= 1 << (7 - t);
    }
    if (M) {
        const int Mlo = M & 7;               // in-lane amp bits
        const int Mhi = (M >> 3) & 31;       // lane bits (stays within half)
        v2f p[8];
        switch (Mlo) {                       // wave-uniform; constant indices per case
        case 0: p[0]=a[0];p[1]=a[1];p[2]=a[2];p[3]=a[3];p[4]=a[4];p[5]=a[5];p[6]=a[6];p[7]=a[7]; break;
        case 1: p[0]=a[1];p[1]=a[0];p[2]=a[3];p[3]=a[2];p[4]=a[5];p[5]=a[4];p[6]=a[7];p[7]=a[6]; break;
        case 2: p[0]=a[2];p[1]=a[3];p[2]=a[0];p[3]=a[1];p[4]=a[6];p[5]=a[7];p[6]=a[4];p[7]=a[5]; break;
        case 3: p[0]=a[3];p[1]=a[2];p[2]=a[1];p[3]=a[0];p[4]=a[7];p[5]=a[6];p[6]=a[5];p[7]=a[4]; break;
        case 4: p[0]=a[4];p[1]=a[5];p[2]=a[6];p[3]=a[7];p[4]=a[0];p[5]=a[1];p[6]=a[2];p[7]=a[3]; break;
        case 5: p[0]=a[5];p[1]=a[4];p[2]=a[7];p[3]=a[6];p[4]=a[1];p[5]=a[0];p[6]=a[3];p[7]=a[2]; break;
        case 6: p[0]=a[6];p[1]=a[7];p[2]=a[4];p[3]=a[5];p[4]=a[2];p[5]=a[3];p[6]=a[0];p[7]=a[1]; break;
        default:p[0]=a[7];p[1]=a[6];p[2]=a[5];p[3]=a[4];p[4]=a[3];p[5]=a[2];p[6]=a[1];p[7]=a[0]; break;
        }
        const int addr = (lane ^ Mhi) << 2;  // Mhi<32 -> half-preserving
#pragma unroll
        for (int k = 0; k < 8; k++) {
            p[k].x = bperm(addr, p[k].x);
            p[k].y = bperm(addr, p[k].y);
        }
        const int pc = 7 - cq;               // control amplitude bit (uniform)
        if (pc >= 3) {
            const bool bsel = (lane >> (pc - 3)) & 1;
#pragma unroll
            for (int k = 0; k < 8; k++) a[k] = bsel ? p[k] : a[k];
        } else if (pc == 2) { a[4]=p[4]; a[5]=p[5]; a[6]=p[6]; a[7]=p[7]; }
        else if (pc == 1)   { a[2]=p[2]; a[3]=p[3]; a[6]=p[6]; a[7]=p[7]; }
        else                { a[1]=p[1]; a[3]=p[3]; a[5]=p[5]; a[7]=p[7]; }
    }

    // ---- conv layers; K-slot map tracked as {k0,k1,k2 | l0..l4} ----
    // init: {7,6,5 | 4,3,2,1,0}
    convm<1,0>(a, ws + 0);       // (6,7): hi=6@k1, lo=7@k0
    swkl<0,0>(a, lane);          // {4,6,5 | 7,3,2,1,0}
    convm<0,2>(a, ws + 16);      // (4,5)
    convm<2,1>(a, ws + 32);      // (5,6)
    swkl<2,2>(a, lane);          // {4,6,2 | 7,3,5,1,0}
    swkl<1,1>(a, lane);          // {4,3,2 | 7,6,5,1,0}
    convm<2,1>(a, ws + 48);      // (2,3)
    convm<1,0>(a, ws + 64);      // (3,4)
    swkl<0,3>(a, lane);          // {1,3,2 | 7,6,5,4,0}
    swkl<1,4>(a, lane);          // {1,0,2 | 7,6,5,4,3}
    convm<1,0>(a, ws + 80);      // (0,1)
    convm<0,2>(a, ws + 96);      // (1,2)
    // ---- layer 2 ----
    convm<1,0>(a, ws + 112);     // (0,1)
    swkl<1,4>(a, lane);          // {1,3,2 | 7,6,5,4,0}
    convm<2,1>(a, ws + 128);     // (2,3)
    convm<0,2>(a, ws + 144);     // (1,2)
    swkl<0,3>(a, lane);          // {4,3,2 | 7,6,5,1,0}
    swkl<2,2>(a, lane);          // {4,3,5 | 7,6,2,1,0}
    convm<0,2>(a, ws + 160);     // (4,5)
    convm<1,0>(a, ws + 176);     // (3,4)
    swkl<1,1>(a, lane);          // {4,6,5 | 7,3,2,1,0}
    swkl<0,0>(a, lane);          // {7,6,5 | 4,3,2,1,0}
    convm<1,0>(a, ws + 192);     // (6,7)
    convm<2,1>(a, ws + 208);     // (5,6) + pool RY(q6) folded

    // ---- pool RY(q0), RY(q2), RY(q4): swap-in + in-lane rotation ----
    swkl<0,4>(a, lane);          // {0,6,5 | 4,3,2,1,7}
    ry_k<0>(a, ws[224], ws[225]);
    swkl<1,2>(a, lane);          // {0,2,5 | 4,3,6,1,7}
    ry_k<1>(a, ws[226], ws[227]);
    swkl<2,0>(a, lane);          // {0,2,4 | 5,3,6,1,7}
    ry_k<2>(a, ws[228], ws[229]);
    // final: k0=q0,k1=q2,k2=q4 | l0=q5,l1=q3,l2=q6,l3=q1,l4=q7

    // ---- z: in-lane 3-bit partials + cross-lane WHT/butterflies ----
    float p0 = fmaf(a[0].x, a[0].x, a[0].y * a[0].y);
    float p1 = fmaf(a[1].x, a[1].x, a[1].y * a[1].y);
    float p2 = fmaf(a[2].x, a[2].x, a[2].y * a[2].y);
    float p3 = fmaf(a[3].x, a[3].x, a[3].y * a[3].y);
    float p4 = fmaf(a[4].x, a[4].x, a[4].y * a[4].y);
    float p5 = fmaf(a[5].x, a[5].x, a[5].y * a[5].y);
    float p6 = fmaf(a[6].x, a[6].x, a[6].y * a[6].y);
    float p7 = fmaf(a[7].x, a[7].x, a[7].y * a[7].y);
    const float s0 = p0 + p1, s1 = p2 + p3, s2 = p4 + p5, s3 = p6 + p7;
    v2f z02;                                       // (zq0, zq2) partials
    z02.x = ((p0 - p1) + (p2 - p3)) + ((p4 - p5) + (p6 - p7));
    z02.y = (s0 - s1) + (s2 - s3);
    float z4p  = (s0 + s1) - (s2 + s3);            // zq4 partial
    float w    = (s0 + s1) + (s2 + s3);            // psum -> WHT
    z02 += sx2<1>(z02);  z02 += sx2<2>(z02);  z02 += sx2<4>(z02);
    z02 += sx2<8>(z02);  z02 += sx2<16>(z02);
    z4p += sxc<1>(z4p);  z4p += sxc<2>(z4p);  z4p += sxc<4>(z4p);
    z4p += sxc<8>(z4p);  z4p += sxc<16>(z4p);
    w = whts<1>(w, lane); w = whts<2>(w, lane); w = whts<4>(w, lane);
    w = whts<8>(w, lane); w = whts<16>(w, lane);
    // lane-qubit z: q5@idx1, q3@idx2, q6@idx4, q1@idx8, q7@idx16 (per half)
    const int gb = (lane & 32) << 2;
    const float z5 = bperm(gb | (1 << 2),  w);
    const float z3 = bperm(gb | (2 << 2),  w);
    const float z6 = bperm(gb | (4 << 2),  w);
    const float z1 = bperm(gb | (8 << 2),  w);
    const float z7 = bperm(gb | (16 << 2), w);
    v4f zlo; zlo.x = z02.x; zlo.y = z1; zlo.z = z02.y; zlo.w = z3;
    v4f zhi; zhi.x = z4p;   zhi.y = z5; zhi.z = z6;    zhi.w = z7;

    // ---- MLP head: 8 -> 64 (relu) -> 32 (relu) -> 1; lane = row hl & hl+32 --
    const v4f* r0 = (const v4f*)(w1 + hl * 8);
    const v4f* r1 = (const v4f*)(w1 + (hl + 32) * 8);
    v4f ha = zlo * r0[0]; ha = __builtin_elementwise_fma(zhi, r0[1], ha);
    v4f hb = zlo * r1[0]; hb = __builtin_elementwise_fma(zhi, r1[1], hb);
    const float h1a = fmaxf(b1[hl]      + (ha.x + ha.y) + (ha.z + ha.w), 0.0f);
    const float h1b = fmaxf(b1[hl + 32] + (hb.x + hb.y) + (hb.z + hb.w), 0.0f);

    __shared__ float h1s[4][2][64];          // wave-local; no barrier needed
    h1s[wv][half][hl]      = h1a;
    h1s[wv][half][hl + 32] = h1b;

    const v4f* hv  = (const v4f*)(&h1s[wv][half][0]);
    const v4f* w2r = (const v4f*)(w2 + hl * 64);
    v4f acc = {0.0f, 0.0f, 0.0f, 0.0f};
#pragma unroll
    for (int j = 0; j < 16; j++)
        acc = __builtin_elementwise_fma(hv[j], w2r[j], acc);
    const float h2 = fmaxf(b2[hl] + (acc.x + acc.y) + (acc.z + acc.w), 0.0f);

    float o = h2 * w3[hl];
    o += sxc<1>(o); o += sxc<2>(o); o += sxc<4>(o); o += sxc<8>(o); o += sxc<16>(o);

    if (hl == 0) out[gA + half * NPAIR] = o + b3[0];
}

extern "C" void kernel_launch(void* const* d_in, const int* in_sizes, int n_in,
                              void* d_out, int out_size, void* d_ws, size_t ws_size,
                              hipStream_t stream) {
    const float* x      = (const float*)d_in[0];
    const float* adj    = (const float*)d_in[1];
    const float* w_proj = (const float*)d_in[2];
    const float* b_proj = (const float*)d_in[3];
    const float* qp     = (const float*)d_in[4];
    const float* w1     = (const float*)d_in[5];
    const float* b1     = (const float*)d_in[6];
    const float* w2     = (const float*)d_in[7];
    const float* b2     = (const float*)d_in[8];
    const float* w3     = (const float*)d_in[9];
    const float* b3     = (const float*)d_in[10];
    float* out = (float*)d_out;
    float* ws  = (float*)d_ws;                 // 230 floats

    hipLaunchKernelGGL(prep_kernel, dim3(1), dim3(64), 0, stream, qp, ws);
    hipLaunchKernelGGL(qcnn_kernel, dim3(NPAIR / 4), dim3(256), 0, stream,
                       x, adj, w_proj, b_proj, ws, w1, b1, w2, b2, w3, b3, out);
}

// Round 9
// 103.104 us; speedup vs baseline: 1.1445x; 1.1445x over previous
//
#include <hip/hip_runtime.h>
#include <math.h>

#define DEV static __device__ __forceinline__

constexpr int SS = 12;
constexpr int NN = 207;
constexpr int NCIRC = 64 * NN;          // 13248 circuits
constexpr int NPAIR = NCIRC / 2;        // 6624 waves; circuit A = lanes 0-31, B = lanes 32-63
// pair (g, g+6624): 6624 = 32*207 -> same node -> shared adjacency mask,
// conv matrices, w1/w2 rows; both circuits share ONE instruction stream.

// Layout: 32 lanes/circuit, 8 amps/lane (NAMED v2f a0..a7, re/im packed).
// Amp bits 0,1,2 = in-lane "K slots"; amp bits 3..7 = lane bits 0..4;
// lane bit 5 = circuit selector. Initially qubit q sits at amp bit (7-q):
// K = {q7@k0, q6@k1, q5@k2}, L: l0=q4,l1=q3,l2=q2,l3=q1,l4=q0.
//
// HARD RULE (R2/R3 LDS-demotion, R8 scratch-spill): the state must be NAMED
// SCALARS. Any v2f a[8] array that crosses a switch or helper-function
// boundary loses SROA -> alloca -> scratch (R8: WRITE_SIZE 26MB, VGPR 32,
// 48us). All state ops below are macros over named variables.

typedef float v2f __attribute__((ext_vector_type(2)));
typedef float v4f __attribute__((ext_vector_type(4)));

DEV v2f splat2(float x) { v2f r; r.x = x; r.y = x; return r; }
DEV v2f vfma(float m, v2f a, v2f acc) { return __builtin_elementwise_fma(splat2(m), a, acc); }
DEV v2f vmul(float m, v2f a) { return splat2(m) * a; }
template<int M> DEV float sxc(float v) { return __shfl_xor(v, M, 64); }
template<int M> DEV v2f sx2(v2f v) { v2f r; r.x = sxc<M>(v.x); r.y = sxc<M>(v.y); return r; }
DEV float bperm(int addr, float v) {
    return __int_as_float(__builtin_amdgcn_ds_bpermute(addr, __float_as_int(v)));
}

// real 4x4 matrix on 4 named slots (basis order b00,b01,b10,b11)
#define CONV4(P, x00, x01, x10, x11) do {                                  \
    v2f _b00 = x00, _b01 = x01, _b10 = x10, _b11 = x11;                    \
    x00 = vfma((P)[0],  _b00, vfma((P)[1],  _b01, vfma((P)[2],  _b10, vmul((P)[3],  _b11)))); \
    x01 = vfma((P)[4],  _b00, vfma((P)[5],  _b01, vfma((P)[6],  _b10, vmul((P)[7],  _b11)))); \
    x10 = vfma((P)[8],  _b00, vfma((P)[9],  _b01, vfma((P)[10], _b10, vmul((P)[11], _b11)))); \
    x11 = vfma((P)[12], _b00, vfma((P)[13], _b01, vfma((P)[14], _b10, vmul((P)[15], _b11)))); \
} while (0)

// conv on K bits (BH=hi qubit, BL=lo qubit); spectator bit -> 2 groups
#define CONVM10(P) do { CONV4(P, a0, a1, a2, a3); CONV4(P, a4, a5, a6, a7); } while (0)
#define CONVM02(P) do { CONV4(P, a0, a4, a1, a5); CONV4(P, a2, a6, a3, a7); } while (0)
#define CONVM21(P) do { CONV4(P, a0, a2, a4, a6); CONV4(P, a1, a3, a5, a7); } while (0)

// half-shuffle swap of one (lo,hi) slot pair across lane bit LB
#define SWP(ML, lb, lo, hi) do {                                           \
    v2f _u = (lb) ? lo : hi;                                               \
    v2f _v = sx2<ML>(_u);                                                  \
    lo = (lb) ? _v : lo;                                                   \
    hi = (lb) ? hi : _v;                                                   \
} while (0)

// swap K bit KB with lane bit LB (4 pairs; 8 ds-ops via half-shuffle)
#define SWKL0(LB) do { const bool _lb = (lane >> (LB)) & 1;                \
    SWP(1 << (LB), _lb, a0, a1); SWP(1 << (LB), _lb, a2, a3);              \
    SWP(1 << (LB), _lb, a4, a5); SWP(1 << (LB), _lb, a6, a7); } while (0)
#define SWKL1(LB) do { const bool _lb = (lane >> (LB)) & 1;                \
    SWP(1 << (LB), _lb, a0, a2); SWP(1 << (LB), _lb, a1, a3);              \
    SWP(1 << (LB), _lb, a4, a6); SWP(1 << (LB), _lb, a5, a7); } while (0)
#define SWKL2(LB) do { const bool _lb = (lane >> (LB)) & 1;                \
    SWP(1 << (LB), _lb, a0, a4); SWP(1 << (LB), _lb, a1, a5);              \
    SWP(1 << (LB), _lb, a2, a6); SWP(1 << (LB), _lb, a3, a7); } while (0)

// in-lane RY rotation of one (lo,hi) pair
#define ROT(c_, s_, lo, hi) do {                                           \
    v2f _lo = lo, _hi = hi;                                                \
    lo = vfma(c_, _lo, vmul(-(s_), _hi));                                  \
    hi = vfma(s_, _lo, vmul(c_, _hi));                                     \
} while (0)
#define RYK0(c_, s_) do { const float _c = (c_), _s = (s_);                \
    ROT(_c, _s, a0, a1); ROT(_c, _s, a2, a3);                              \
    ROT(_c, _s, a4, a5); ROT(_c, _s, a6, a7); } while (0)
#define RYK1(c_, s_) do { const float _c = (c_), _s = (s_);                \
    ROT(_c, _s, a0, a2); ROT(_c, _s, a1, a3);                              \
    ROT(_c, _s, a4, a6); ROT(_c, _s, a5, a7); } while (0)
#define RYK2(c_, s_) do { const float _c = (c_), _s = (s_);                \
    ROT(_c, _s, a0, a4); ROT(_c, _s, a1, a5);                              \
    ROT(_c, _s, a2, a6); ROT(_c, _s, a3, a7); } while (0)

// WHT butterfly stage (R7-verified)
template<int MK> DEV float whts(float p, int lane) {
    float t = sxc<MK>(p);
    return (lane & MK) ? (t - p) : (p + t);
}

// ---- prep: fuse conv pair (RYhi,RYlo,CNOT(hi->lo),RYhi,RYlo,CNOT(lo->hi))
// into one real 4x4; basis idx = 2*b_hi + b_lo, hi = qubit i, lo = i+1.
// ws[16n..]: matrix for conv n (execution-schedule order); ws[224..229]:
// pool (c,s) for q0,q2,q4; conv 13 has pool-RY(q6) (lo slot) folded in.
// (R8-verified numerically.)
__global__ void prep_kernel(const float* __restrict__ qp, float* __restrict__ ws) {
    const int n = threadIdx.x;
    if (n == 14) {
        float s, c;
        sincosf(0.5f * qp[56], &s, &c); ws[224] = c; ws[225] = s;
        sincosf(0.5f * qp[58], &s, &c); ws[226] = c; ws[227] = s;
        sincosf(0.5f * qp[60], &s, &c); ws[228] = c; ws[229] = s;
    }
    if (n >= 14) return;
    // schedule: L1 (6,7)(4,5)(5,6)(2,3)(3,4)(0,1)(1,2); L2 (0,1)(2,3)(1,2)(4,5)(3,4)(6,7)(5,6)
    const int Jt[14] = {12, 8, 24, 4, 20, 0, 16, 28, 32, 44, 36, 48, 40, 52};
    const int J = Jt[n];
    float cg[4], sg[4];
    for (int i = 0; i < 4; i++) sincosf(0.5f * qp[J + i], &sg[i], &cg[i]);
    float A[16], B[16], M[16];
    {
        float H[2][2] = {{cg[0], -sg[0]}, {sg[0], cg[0]}};
        float L[2][2] = {{cg[1], -sg[1]}, {sg[1], cg[1]}};
        for (int a_ = 0; a_ < 2; a_++) for (int b_ = 0; b_ < 2; b_++)
            for (int p = 0; p < 2; p++) for (int q = 0; q < 2; q++)
                A[(2*a_+b_)*4 + (2*p+q)] = H[a_][p] * L[b_][q];
    }
    for (int j = 0; j < 4; j++) { float t = A[8+j]; A[8+j] = A[12+j]; A[12+j] = t; }  // CNOT hi->lo
    {
        float H[2][2] = {{cg[2], -sg[2]}, {sg[2], cg[2]}};
        float L[2][2] = {{cg[3], -sg[3]}, {sg[3], cg[3]}};
        for (int a_ = 0; a_ < 2; a_++) for (int b_ = 0; b_ < 2; b_++)
            for (int p = 0; p < 2; p++) for (int q = 0; q < 2; q++)
                B[(2*a_+b_)*4 + (2*p+q)] = H[a_][p] * L[b_][q];
    }
    for (int r = 0; r < 4; r++)
        for (int c = 0; c < 4; c++) {
            float acc = 0.0f;
            for (int k = 0; k < 4; k++) acc += B[r*4+k] * A[k*4+c];
            M[r*4+c] = acc;
        }
    for (int j = 0; j < 4; j++) { float t = M[4+j]; M[4+j] = M[12+j]; M[12+j] = t; }  // CNOT lo->hi
    if (n == 13) {          // fold pool RY(q6); q6 = lo slot of conv (5,6)
        float ps, pc;
        sincosf(0.5f * qp[62], &ps, &pc);
        for (int g = 0; g < 4; g += 2)
            for (int j = 0; j < 4; j++) {
                float r0 = M[g*4+j], r1 = M[(g+1)*4+j];
                M[g*4+j]     = pc * r0 - ps * r1;
                M[(g+1)*4+j] = ps * r0 + pc * r1;
            }
    }
    for (int i = 0; i < 16; i++) ws[16*n + i] = M[i];
}

__global__ __launch_bounds__(256) void qcnn_kernel(
    const float* __restrict__ x, const float* __restrict__ adj,
    const float* __restrict__ w_proj, const float* __restrict__ b_proj,
    const float* __restrict__ ws,
    const float* __restrict__ w1, const float* __restrict__ b1,
    const float* __restrict__ w2, const float* __restrict__ b2,
    const float* __restrict__ w3, const float* __restrict__ b3,
    float* __restrict__ out)
{
    const int lane = threadIdx.x & 63;
    const int half = lane >> 5;                  // 0 = circuit A, 1 = circuit B
    const int hl   = lane & 31;
    const int wv   = threadIdx.x >> 6;
    const int gA   = blockIdx.x * 4 + wv;        // grid exact: 1656*4 == 6624
    const int bA   = gA / NN;
    const int node = gA - bA * NN;
    const int bb   = bA + (half << 5);           // circuit B: b += 32, same node

    // ---- angles = x-slice @ w_proj.T + b_proj, clipped to [-pi, pi] ----
    const float* xp = x + ((size_t)bb * SS * NN + node) * 2;
    v2f av0 = splat2(0.0f), av1 = av0, av2 = av0, av3 = av0,
        av4 = av0, av5 = av0, av6 = av0, av7 = av0;
#pragma unroll
    for (int s = 0; s < SS; s++) {
        const v2f xv = *(const v2f*)(xp + (size_t)s * (NN * 2));
        const float* wp = w_proj + 2 * s;
        av0 = __builtin_elementwise_fma(xv, *(const v2f*)(wp + 0 * 24), av0);
        av1 = __builtin_elementwise_fma(xv, *(const v2f*)(wp + 1 * 24), av1);
        av2 = __builtin_elementwise_fma(xv, *(const v2f*)(wp + 2 * 24), av2);
        av3 = __builtin_elementwise_fma(xv, *(const v2f*)(wp + 3 * 24), av3);
        av4 = __builtin_elementwise_fma(xv, *(const v2f*)(wp + 4 * 24), av4);
        av5 = __builtin_elementwise_fma(xv, *(const v2f*)(wp + 5 * 24), av5);
        av6 = __builtin_elementwise_fma(xv, *(const v2f*)(wp + 6 * 24), av6);
        av7 = __builtin_elementwise_fma(xv, *(const v2f*)(wp + 7 * 24), av7);
    }
    const float PI_F = 3.14159265358979323846f;
    float ang0 = fminf(fmaxf(av0.x + av0.y + b_proj[0], -PI_F), PI_F);
    float ang1 = fminf(fmaxf(av1.x + av1.y + b_proj[1], -PI_F), PI_F);
    float ang2 = fminf(fmaxf(av2.x + av2.y + b_proj[2], -PI_F), PI_F);
    float ang3 = fminf(fmaxf(av3.x + av3.y + b_proj[3], -PI_F), PI_F);
    float ang4 = fminf(fmaxf(av4.x + av4.y + b_proj[4], -PI_F), PI_F);
    float ang5 = fminf(fmaxf(av5.x + av5.y + b_proj[5], -PI_F), PI_F);
    float ang6 = fminf(fmaxf(av6.x + av6.y + b_proj[6], -PI_F), PI_F);
    float ang7 = fminf(fmaxf(av7.x + av7.y + b_proj[7], -PI_F), PI_F);

    // ---- analytic product state (RY layer + RZ phases) ----
    float c0, s0, c1, s1, c2, s2, c3, s3, c4, s4, c5, s5, c6, s6, c7, s7;
    __sincosf(0.5f * ang0, &s0, &c0); __sincosf(0.5f * ang1, &s1, &c1);
    __sincosf(0.5f * ang2, &s2, &c2); __sincosf(0.5f * ang3, &s3, &c3);
    __sincosf(0.5f * ang4, &s4, &c4); __sincosf(0.5f * ang5, &s5, &c5);
    __sincosf(0.5f * ang6, &s6, &c6); __sincosf(0.5f * ang7, &s7, &c7);
    // qubits 0..4 -> lane bits 4..0
    float A = (((lane >> 4) & 1) ? s0 : c0) * (((lane >> 3) & 1) ? s1 : c1)
            * (((lane >> 2) & 1) ? s2 : c2) * (((lane >> 1) & 1) ? s3 : c3)
            * (((lane >> 0) & 1) ? s4 : c4);
    // RZ on qubits 0..3 -> lane bits 4..1
    float phi = (((lane >> 4) & 1) ? 0.5f : -0.5f) * ang4
              + (((lane >> 3) & 1) ? 0.5f : -0.5f) * ang5
              + (((lane >> 2) & 1) ? 0.5f : -0.5f) * ang6
              + (((lane >> 1) & 1) ? 0.5f : -0.5f) * ang7;
    float cp, sp;
    __sincosf(phi, &sp, &cp);
    v2f ph; ph.x = cp; ph.y = sp;

    // amp bit0=q7, bit1=q6, bit2=q5
    const float c5c6 = c5 * c6, c5s6 = c5 * s6, s5c6 = s5 * c6, s5s6 = s5 * s6;
    v2f a0 = vmul(A * c5c6 * c7, ph), a1 = vmul(A * c5c6 * s7, ph);
    v2f a2 = vmul(A * c5s6 * c7, ph), a3 = vmul(A * c5s6 * s7, ph);
    v2f a4 = vmul(A * s5c6 * c7, ph), a5 = vmul(A * s5c6 * s7, ph);
    v2f a6 = vmul(A * s5s6 * c7, ph), a7 = vmul(A * s5s6 * s7, ph);

    // ---- adjacency-controlled CNOT chain == one XOR-mask permutation ----
    const int cq = node & 7;
    int M = 0;
#pragma unroll
    for (int t = 0; t < 8; t++) {
        float avv = adj[cq * NN + t];
        if (t != cq && avv > 0.0f) M |= 1 << (7 - t);
    }
    if (M) {
        const int Mlo = M & 7;               // in-lane amp bits
        const int Mhi = (M >> 3) & 31;       // lane bits (stays within half)
        v2f p0, p1, p2, p3, p4, p5, p6, p7;
        switch (Mlo) {                       // wave-uniform; p_k = a_(k^Mlo)
        case 0: p0=a0;p1=a1;p2=a2;p3=a3;p4=a4;p5=a5;p6=a6;p7=a7; break;
        case 1: p0=a1;p1=a0;p2=a3;p3=a2;p4=a5;p5=a4;p6=a7;p7=a6; break;
        case 2: p0=a2;p1=a3;p2=a0;p3=a1;p4=a6;p5=a7;p6=a4;p7=a5; break;
        case 3: p0=a3;p1=a2;p2=a1;p3=a0;p4=a7;p5=a6;p6=a5;p7=a4; break;
        case 4: p0=a4;p1=a5;p2=a6;p3=a7;p4=a0;p5=a1;p6=a2;p7=a3; break;
        case 5: p0=a5;p1=a4;p2=a7;p3=a6;p4=a1;p5=a0;p6=a3;p7=a2; break;
        case 6: p0=a6;p1=a7;p2=a4;p3=a5;p4=a2;p5=a3;p6=a0;p7=a1; break;
        default:p0=a7;p1=a6;p2=a5;p3=a4;p4=a3;p5=a2;p6=a1;p7=a0; break;
        }
        const int addr = (lane ^ Mhi) << 2;  // Mhi<32 -> half-preserving
        p0.x = bperm(addr, p0.x); p0.y = bperm(addr, p0.y);
        p1.x = bperm(addr, p1.x); p1.y = bperm(addr, p1.y);
        p2.x = bperm(addr, p2.x); p2.y = bperm(addr, p2.y);
        p3.x = bperm(addr, p3.x); p3.y = bperm(addr, p3.y);
        p4.x = bperm(addr, p4.x); p4.y = bperm(addr, p4.y);
        p5.x = bperm(addr, p5.x); p5.y = bperm(addr, p5.y);
        p6.x = bperm(addr, p6.x); p6.y = bperm(addr, p6.y);
        p7.x = bperm(addr, p7.x); p7.y = bperm(addr, p7.y);
        const int pc = 7 - cq;               // control amplitude bit (uniform)
        if (pc >= 3) {
            const bool bs = (lane >> (pc - 3)) & 1;
            a0 = bs ? p0 : a0; a1 = bs ? p1 : a1; a2 = bs ? p2 : a2; a3 = bs ? p3 : a3;
            a4 = bs ? p4 : a4; a5 = bs ? p5 : a5; a6 = bs ? p6 : a6; a7 = bs ? p7 : a7;
        } else if (pc == 2) { a4 = p4; a5 = p5; a6 = p6; a7 = p7; }
        else if (pc == 1)   { a2 = p2; a3 = p3; a6 = p6; a7 = p7; }
        else                { a1 = p1; a3 = p3; a5 = p5; a7 = p7; }
    }

    // ---- conv layers; K-slot map {k0,k1,k2 | l0..l4} (R8-verified schedule) --
    // init: {7,6,5 | 4,3,2,1,0}
    CONVM10(ws + 0);             // (6,7)
    SWKL0(0);                    // {4,6,5 | 7,3,2,1,0}
    CONVM02(ws + 16);            // (4,5)
    CONVM21(ws + 32);            // (5,6)
    SWKL2(2);                    // {4,6,2 | 7,3,5,1,0}
    SWKL1(1);                    // {4,3,2 | 7,6,5,1,0}
    CONVM21(ws + 48);            // (2,3)
    CONVM10(ws + 64);            // (3,4)
    SWKL0(3);                    // {1,3,2 | 7,6,5,4,0}
    SWKL1(4);                    // {1,0,2 | 7,6,5,4,3}
    CONVM10(ws + 80);            // (0,1)
    CONVM02(ws + 96);            // (1,2)
    // ---- layer 2 ----
    CONVM10(ws + 112);           // (0,1)
    SWKL1(4);                    // {1,3,2 | 7,6,5,4,0}
    CONVM21(ws + 128);           // (2,3)
    CONVM02(ws + 144);           // (1,2)
    SWKL0(3);                    // {4,3,2 | 7,6,5,1,0}
    SWKL2(2);                    // {4,3,5 | 7,6,2,1,0}
    CONVM02(ws + 160);           // (4,5)
    CONVM10(ws + 176);           // (3,4)
    SWKL1(1);                    // {4,6,5 | 7,3,2,1,0}
    SWKL0(0);                    // {7,6,5 | 4,3,2,1,0}
    CONVM10(ws + 192);           // (6,7)
    CONVM21(ws + 208);           // (5,6) + pool RY(q6) folded

    // ---- pool RY(q0), RY(q2), RY(q4): swap-in + in-lane rotation ----
    SWKL0(4);                    // {0,6,5 | 4,3,2,1,7}
    RYK0(ws[224], ws[225]);
    SWKL1(2);                    // {0,2,5 | 4,3,6,1,7}
    RYK1(ws[226], ws[227]);
    SWKL2(0);                    // {0,2,4 | 5,3,6,1,7}
    RYK2(ws[228], ws[229]);
    // final: k0=q0,k1=q2,k2=q4 | l0=q5,l1=q3,l2=q6,l3=q1,l4=q7

    // ---- z: in-lane 3-bit partials + cross-lane WHT/butterflies ----
    const float q0 = fmaf(a0.x, a0.x, a0.y * a0.y);
    const float q1 = fmaf(a1.x, a1.x, a1.y * a1.y);
    const float q2 = fmaf(a2.x, a2.x, a2.y * a2.y);
    const float q3 = fmaf(a3.x, a3.x, a3.y * a3.y);
    const float q4 = fmaf(a4.x, a4.x, a4.y * a4.y);
    const float q5 = fmaf(a5.x, a5.x, a5.y * a5.y);
    const float q6 = fmaf(a6.x, a6.x, a6.y * a6.y);
    const float q7 = fmaf(a7.x, a7.x, a7.y * a7.y);
    const float t0 = q0 + q1, t1 = q2 + q3, t2 = q4 + q5, t3 = q6 + q7;
    v2f z02;                                       // (zq0, zq2) partials
    z02.x = ((q0 - q1) + (q2 - q3)) + ((q4 - q5) + (q6 - q7));
    z02.y = (t0 - t1) + (t2 - t3);
    float z4p = (t0 + t1) - (t2 + t3);             // zq4 partial
    float w   = (t0 + t1) + (t2 + t3);             // psum -> WHT
    z02 += sx2<1>(z02);  z02 += sx2<2>(z02);  z02 += sx2<4>(z02);
    z02 += sx2<8>(z02);  z02 += sx2<16>(z02);
    z4p += sxc<1>(z4p);  z4p += sxc<2>(z4p);  z4p += sxc<4>(z4p);
    z4p += sxc<8>(z4p);  z4p += sxc<16>(z4p);
    w = whts<1>(w, lane); w = whts<2>(w, lane); w = whts<4>(w, lane);
    w = whts<8>(w, lane); w = whts<16>(w, lane);
    // lane-qubit z: q5@idx1, q3@idx2, q6@idx4, q1@idx8, q7@idx16 (per half)
    const int gb = (lane & 32) << 2;
    const float z5 = bperm(gb | (1 << 2),  w);
    const float z3 = bperm(gb | (2 << 2),  w);
    const float z6 = bperm(gb | (4 << 2),  w);
    const float z1 = bperm(gb | (8 << 2),  w);
    const float z7 = bperm(gb | (16 << 2), w);
    v4f zlo; zlo.x = z02.x; zlo.y = z1; zlo.z = z02.y; zlo.w = z3;
    v4f zhi; zhi.x = z4p;   zhi.y = z5; zhi.z = z6;    zhi.w = z7;

    // ---- MLP head: 8 -> 64 (relu) -> 32 (relu) -> 1; lane = rows hl, hl+32 --
    const v4f* r0 = (const v4f*)(w1 + hl * 8);
    const v4f* r1 = (const v4f*)(w1 + (hl + 32) * 8);
    v4f ha = zlo * r0[0]; ha = __builtin_elementwise_fma(zhi, r0[1], ha);
    v4f hb = zlo * r1[0]; hb = __builtin_elementwise_fma(zhi, r1[1], hb);
    const float h1a = fmaxf(b1[hl]      + (ha.x + ha.y) + (ha.z + ha.w), 0.0f);
    const float h1b = fmaxf(b1[hl + 32] + (hb.x + hb.y) + (hb.z + hb.w), 0.0f);

    __shared__ float h1s[4][2][64];          // wave-local; no barrier needed
    h1s[wv][half][hl]      = h1a;
    h1s[wv][half][hl + 32] = h1b;

    const v4f* hv  = (const v4f*)(&h1s[wv][half][0]);
    const v4f* w2r = (const v4f*)(w2 + hl * 64);
    v4f acc = {0.0f, 0.0f, 0.0f, 0.0f};
#pragma unroll
    for (int j = 0; j < 16; j++)
        acc = __builtin_elementwise_fma(hv[j], w2r[j], acc);
    const float h2 = fmaxf(b2[hl] + (acc.x + acc.y) + (acc.z + acc.w), 0.0f);

    float o = h2 * w3[hl];
    o += sxc<1>(o); o += sxc<2>(o); o += sxc<4>(o); o += sxc<8>(o); o += sxc<16>(o);

    if (hl == 0) out[gA + half * NPAIR] = o + b3[0];
}

extern "C" void kernel_launch(void* const* d_in, const int* in_sizes, int n_in,
                              void* d_out, int out_size, void* d_ws, size_t ws_size,
                              hipStream_t stream) {
    const float* x      = (const float*)d_in[0];
    const float* adj    = (const float*)d_in[1];
    const float* w_proj = (const float*)d_in[2];
    const float* b_proj = (const float*)d_in[3];
    const float* qp     = (const float*)d_in[4];
    const float* w1     = (const float*)d_in[5];
    const float* b1     = (const float*)d_in[6];
    const float* w2     = (const float*)d_in[7];
    const float* b2     = (const float*)d_in[8];
    const float* w3     = (const float*)d_in[9];
    const float* b3     = (const float*)d_in[10];
    float* out = (float*)d_out;
    float* ws  = (float*)d_ws;                 // 230 floats

    hipLaunchKernelGGL(prep_kernel, dim3(1), dim3(64), 0, stream, qp, ws);
    hipLaunchKernelGGL(qcnn_kernel, dim3(NPAIR / 4), dim3(256), 0, stream,
                       x, adj, w_proj, b_proj, ws, w1, b1, w2, b2, w3, b3, out);
}

// Round 10
// 100.898 us; speedup vs baseline: 1.1695x; 1.0219x over previous
//
#include <hip/hip_runtime.h>
#include <math.h>

#define DEV static __device__ __forceinline__

constexpr int SS = 12;
constexpr int NN = 207;
constexpr int NCIRC = 64 * NN;          // 13248 circuits
constexpr int NPAIR = NCIRC / 2;        // 6624 waves; circuit A = lanes 0-31, B = lanes 32-63
// pair (g, g+6624): 6624 = 32*207 -> same node -> shared adjacency mask,
// conv matrices, w1/w2 rows; both circuits share ONE instruction stream.

// Layout: 32 lanes/circuit, 8 amps/lane (NAMED v2f a0..a7, re/im packed).
// Amp bits 0,1,2 = in-lane "K slots"; amp bits 3..7 = lane bits 0..4;
// lane bit 5 = circuit selector. Initially qubit q sits at amp bit (7-q):
// K = {q7@k0, q6@k1, q5@k2}, L: l0=q4,l1=q3,l2=q2,l3=q1,l4=q0.
//
// HARD RULE (R2/R3 LDS-demotion, R8 scratch-spill): state must be NAMED
// SCALARS; runtime permutes via wave-uniform switch over named temps.
// R10: all 4 pool RYs are folded into conv matrices in prep (they commute
// past the remaining convs) -> 3 swap + 3 rot stages removed from the
// critical path; final layout = {7,6,5 | 4,3,2,1,0}.

typedef float v2f __attribute__((ext_vector_type(2)));
typedef float v4f __attribute__((ext_vector_type(4)));

DEV v2f splat2(float x) { v2f r; r.x = x; r.y = x; return r; }
DEV v2f vfma(float m, v2f a, v2f acc) { return __builtin_elementwise_fma(splat2(m), a, acc); }
DEV v2f vmul(float m, v2f a) { return splat2(m) * a; }
template<int M> DEV float sxc(float v) { return __shfl_xor(v, M, 64); }
template<int M> DEV v2f sx2(v2f v) { v2f r; r.x = sxc<M>(v.x); r.y = sxc<M>(v.y); return r; }
DEV float bperm(int addr, float v) {
    return __int_as_float(__builtin_amdgcn_ds_bpermute(addr, __float_as_int(v)));
}

// real 4x4 matrix on 4 named slots (basis order b00,b01,b10,b11)
#define CONV4(P, x00, x01, x10, x11) do {                                  \
    v2f _b00 = x00, _b01 = x01, _b10 = x10, _b11 = x11;                    \
    x00 = vfma((P)[0],  _b00, vfma((P)[1],  _b01, vfma((P)[2],  _b10, vmul((P)[3],  _b11)))); \
    x01 = vfma((P)[4],  _b00, vfma((P)[5],  _b01, vfma((P)[6],  _b10, vmul((P)[7],  _b11)))); \
    x10 = vfma((P)[8],  _b00, vfma((P)[9],  _b01, vfma((P)[10], _b10, vmul((P)[11], _b11)))); \
    x11 = vfma((P)[12], _b00, vfma((P)[13], _b01, vfma((P)[14], _b10, vmul((P)[15], _b11)))); \
} while (0)

// conv on K bits; hi/lo mapping: CONVM10 hi=k1,lo=k0; CONVM02 hi=k0,lo=k2;
// CONVM21 hi=k2,lo=k1. Spectator bit -> 2 groups.
#define CONVM10(P) do { CONV4(P, a0, a1, a2, a3); CONV4(P, a4, a5, a6, a7); } while (0)
#define CONVM02(P) do { CONV4(P, a0, a4, a1, a5); CONV4(P, a2, a6, a3, a7); } while (0)
#define CONVM21(P) do { CONV4(P, a0, a2, a4, a6); CONV4(P, a1, a3, a5, a7); } while (0)

// half-shuffle swap of one (lo,hi) slot pair across lane bit LB
#define SWP(ML, lb, lo, hi) do {                                           \
    v2f _u = (lb) ? lo : hi;                                               \
    v2f _v = sx2<ML>(_u);                                                  \
    lo = (lb) ? _v : lo;                                                   \
    hi = (lb) ? hi : _v;                                                   \
} while (0)

// swap K bit KB with lane bit LB (4 pairs; half-shuffle)
#define SWKL0(LB) do { const bool _lb = (lane >> (LB)) & 1;                \
    SWP(1 << (LB), _lb, a0, a1); SWP(1 << (LB), _lb, a2, a3);              \
    SWP(1 << (LB), _lb, a4, a5); SWP(1 << (LB), _lb, a6, a7); } while (0)
#define SWKL1(LB) do { const bool _lb = (lane >> (LB)) & 1;                \
    SWP(1 << (LB), _lb, a0, a2); SWP(1 << (LB), _lb, a1, a3);              \
    SWP(1 << (LB), _lb, a4, a6); SWP(1 << (LB), _lb, a5, a7); } while (0)
#define SWKL2(LB) do { const bool _lb = (lane >> (LB)) & 1;                \
    SWP(1 << (LB), _lb, a0, a4); SWP(1 << (LB), _lb, a1, a5);              \
    SWP(1 << (LB), _lb, a2, a6); SWP(1 << (LB), _lb, a3, a7); } while (0)

// WHT butterfly stage (R7-verified)
template<int MK> DEV float whts(float p, int lane) {
    float t = sxc<MK>(p);
    return (lane & MK) ? (t - p) : (p + t);
}

// ---- prep: fuse conv pair (RYhi,RYlo,CNOT(hi->lo),RYhi,RYlo,CNOT(lo->hi))
// into one real 4x4; basis idx = 2*b_hi + b_lo, hi = qubit i, lo = i+1.
// ws[16n..]: matrix for conv n (execution-schedule order). Pool RYs folded:
// n=7 (L2 (0,1)): RY(q0) on HI; n=9 (L2 (1,2)): RY(q2) on LO;
// n=11 (L2 (3,4)): RY(q4) on LO; n=13 (L2 (5,6)): RY(q6) on LO.
__global__ void prep_kernel(const float* __restrict__ qp, float* __restrict__ ws) {
    const int n = threadIdx.x;
    if (n >= 14) return;
    // schedule: L1 (6,7)(4,5)(5,6)(2,3)(3,4)(0,1)(1,2); L2 (0,1)(2,3)(1,2)(4,5)(3,4)(6,7)(5,6)
    const int Jt[14] = {12, 8, 24, 4, 20, 0, 16, 28, 32, 44, 36, 48, 40, 52};
    const int J = Jt[n];
    float cg[4], sg[4];
    for (int i = 0; i < 4; i++) sincosf(0.5f * qp[J + i], &sg[i], &cg[i]);
    float A[16], B[16], M[16];
    {
        float H[2][2] = {{cg[0], -sg[0]}, {sg[0], cg[0]}};
        float L[2][2] = {{cg[1], -sg[1]}, {sg[1], cg[1]}};
        for (int a_ = 0; a_ < 2; a_++) for (int b_ = 0; b_ < 2; b_++)
            for (int p = 0; p < 2; p++) for (int q = 0; q < 2; q++)
                A[(2*a_+b_)*4 + (2*p+q)] = H[a_][p] * L[b_][q];
    }
    for (int j = 0; j < 4; j++) { float t = A[8+j]; A[8+j] = A[12+j]; A[12+j] = t; }  // CNOT hi->lo
    {
        float H[2][2] = {{cg[2], -sg[2]}, {sg[2], cg[2]}};
        float L[2][2] = {{cg[3], -sg[3]}, {sg[3], cg[3]}};
        for (int a_ = 0; a_ < 2; a_++) for (int b_ = 0; b_ < 2; b_++)
            for (int p = 0; p < 2; p++) for (int q = 0; q < 2; q++)
                B[(2*a_+b_)*4 + (2*p+q)] = H[a_][p] * L[b_][q];
    }
    for (int r = 0; r < 4; r++)
        for (int c = 0; c < 4; c++) {
            float acc = 0.0f;
            for (int k = 0; k < 4; k++) acc += B[r*4+k] * A[k*4+c];
            M[r*4+c] = acc;
        }
    for (int j = 0; j < 4; j++) { float t = M[4+j]; M[4+j] = M[12+j]; M[12+j] = t; }  // CNOT lo->hi
    // fold pool RYs (left-multiply R onto M; applied AFTER the conv)
    int mode = 0; float fc = 1.0f, fs = 0.0f;
    if (n == 7)  { sincosf(0.5f * qp[56], &fs, &fc); mode = 2; }   // RY(q0) on hi
    if (n == 9)  { sincosf(0.5f * qp[58], &fs, &fc); mode = 1; }   // RY(q2) on lo
    if (n == 11) { sincosf(0.5f * qp[60], &fs, &fc); mode = 1; }   // RY(q4) on lo
    if (n == 13) { sincosf(0.5f * qp[62], &fs, &fc); mode = 1; }   // RY(q6) on lo
    if (mode == 1) {            // lo: row pairs (0,1), (2,3)
        for (int j = 0; j < 4; j++) {
            float r0 = M[j],     r1 = M[4+j];
            M[j]    = fc * r0 - fs * r1;  M[4+j]  = fs * r0 + fc * r1;
            float r2 = M[8+j],   r3 = M[12+j];
            M[8+j]  = fc * r2 - fs * r3;  M[12+j] = fs * r2 + fc * r3;
        }
    } else if (mode == 2) {     // hi: row pairs (0,2), (1,3)
        for (int j = 0; j < 4; j++) {
            float r0 = M[j],     r2 = M[8+j];
            M[j]    = fc * r0 - fs * r2;  M[8+j]  = fs * r0 + fc * r2;
            float r1 = M[4+j],   r3 = M[12+j];
            M[4+j]  = fc * r1 - fs * r3;  M[12+j] = fs * r1 + fc * r3;
        }
    }
    for (int i = 0; i < 16; i++) ws[16*n + i] = M[i];
}

__global__ __launch_bounds__(256, 6) void qcnn_kernel(
    const float* __restrict__ x, const float* __restrict__ adj,
    const float* __restrict__ w_proj, const float* __restrict__ b_proj,
    const float* __restrict__ ws,
    const float* __restrict__ w1, const float* __restrict__ b1,
    const float* __restrict__ w2, const float* __restrict__ b2,
    const float* __restrict__ w3, const float* __restrict__ b3,
    float* __restrict__ out)
{
    const int lane = threadIdx.x & 63;
    const int half = lane >> 5;                  // 0 = circuit A, 1 = circuit B
    const int hl   = lane & 31;
    const int wv   = threadIdx.x >> 6;
    const int gA   = blockIdx.x * 4 + wv;        // grid exact: 1656*4 == 6624
    const int bA   = gA / NN;
    const int node = gA - bA * NN;
    const int bb   = bA + (half << 5);           // circuit B: b += 32, same node

    // ---- angles = x-slice @ w_proj.T + b_proj, clipped to [-pi, pi] ----
    const float* xp = x + ((size_t)bb * SS * NN + node) * 2;
    v2f av0 = splat2(0.0f), av1 = av0, av2 = av0, av3 = av0,
        av4 = av0, av5 = av0, av6 = av0, av7 = av0;
#pragma unroll
    for (int s = 0; s < SS; s++) {
        const v2f xv = *(const v2f*)(xp + (size_t)s * (NN * 2));
        const float* wp = w_proj + 2 * s;
        av0 = __builtin_elementwise_fma(xv, *(const v2f*)(wp + 0 * 24), av0);
        av1 = __builtin_elementwise_fma(xv, *(const v2f*)(wp + 1 * 24), av1);
        av2 = __builtin_elementwise_fma(xv, *(const v2f*)(wp + 2 * 24), av2);
        av3 = __builtin_elementwise_fma(xv, *(const v2f*)(wp + 3 * 24), av3);
        av4 = __builtin_elementwise_fma(xv, *(const v2f*)(wp + 4 * 24), av4);
        av5 = __builtin_elementwise_fma(xv, *(const v2f*)(wp + 5 * 24), av5);
        av6 = __builtin_elementwise_fma(xv, *(const v2f*)(wp + 6 * 24), av6);
        av7 = __builtin_elementwise_fma(xv, *(const v2f*)(wp + 7 * 24), av7);
    }
    const float PI_F = 3.14159265358979323846f;
    float ang0 = fminf(fmaxf(av0.x + av0.y + b_proj[0], -PI_F), PI_F);
    float ang1 = fminf(fmaxf(av1.x + av1.y + b_proj[1], -PI_F), PI_F);
    float ang2 = fminf(fmaxf(av2.x + av2.y + b_proj[2], -PI_F), PI_F);
    float ang3 = fminf(fmaxf(av3.x + av3.y + b_proj[3], -PI_F), PI_F);
    float ang4 = fminf(fmaxf(av4.x + av4.y + b_proj[4], -PI_F), PI_F);
    float ang5 = fminf(fmaxf(av5.x + av5.y + b_proj[5], -PI_F), PI_F);
    float ang6 = fminf(fmaxf(av6.x + av6.y + b_proj[6], -PI_F), PI_F);
    float ang7 = fminf(fmaxf(av7.x + av7.y + b_proj[7], -PI_F), PI_F);

    // ---- analytic product state (RY layer + RZ phases) ----
    float c0, s0, c1, s1, c2, s2, c3, s3, c4, s4, c5, s5, c6, s6, c7, s7;
    __sincosf(0.5f * ang0, &s0, &c0); __sincosf(0.5f * ang1, &s1, &c1);
    __sincosf(0.5f * ang2, &s2, &c2); __sincosf(0.5f * ang3, &s3, &c3);
    __sincosf(0.5f * ang4, &s4, &c4); __sincosf(0.5f * ang5, &s5, &c5);
    __sincosf(0.5f * ang6, &s6, &c6); __sincosf(0.5f * ang7, &s7, &c7);
    // qubits 0..4 -> lane bits 4..0
    float A = (((lane >> 4) & 1) ? s0 : c0) * (((lane >> 3) & 1) ? s1 : c1)
            * (((lane >> 2) & 1) ? s2 : c2) * (((lane >> 1) & 1) ? s3 : c3)
            * (((lane >> 0) & 1) ? s4 : c4);
    // RZ on qubits 0..3 -> lane bits 4..1
    float phi = (((lane >> 4) & 1) ? 0.5f : -0.5f) * ang4
              + (((lane >> 3) & 1) ? 0.5f : -0.5f) * ang5
              + (((lane >> 2) & 1) ? 0.5f : -0.5f) * ang6
              + (((lane >> 1) & 1) ? 0.5f : -0.5f) * ang7;
    float cp, sp;
    __sincosf(phi, &sp, &cp);
    v2f ph; ph.x = cp; ph.y = sp;

    // amp bit0=q7, bit1=q6, bit2=q5
    const float c5c6 = c5 * c6, c5s6 = c5 * s6, s5c6 = s5 * c6, s5s6 = s5 * s6;
    v2f a0 = vmul(A * c5c6 * c7, ph), a1 = vmul(A * c5c6 * s7, ph);
    v2f a2 = vmul(A * c5s6 * c7, ph), a3 = vmul(A * c5s6 * s7, ph);
    v2f a4 = vmul(A * s5c6 * c7, ph), a5 = vmul(A * s5c6 * s7, ph);
    v2f a6 = vmul(A * s5s6 * c7, ph), a7 = vmul(A * s5s6 * s7, ph);

    // ---- adjacency-controlled CNOT chain == one XOR-mask permutation ----
    const int cq = node & 7;
    int M = 0;
#pragma unroll
    for (int t = 0; t < 8; t++) {
        float avv = adj[cq * NN + t];
        if (t != cq && avv > 0.0f) M |= 1 << (7 - t);
    }
    if (M) {
        const int Mlo = M & 7;               // in-lane amp bits
        const int Mhi = (M >> 3) & 31;       // lane bits (stays within half)
        v2f p0, p1, p2, p3, p4, p5, p6, p7;
        switch (Mlo) {                       // wave-uniform; p_k = a_(k^Mlo)
        case 0: p0=a0;p1=a1;p2=a2;p3=a3;p4=a4;p5=a5;p6=a6;p7=a7; break;
        case 1: p0=a1;p1=a0;p2=a3;p3=a2;p4=a5;p5=a4;p6=a7;p7=a6; break;
        case 2: p0=a2;p1=a3;p2=a0;p3=a1;p4=a6;p5=a7;p6=a4;p7=a5; break;
        case 3: p0=a3;p1=a2;p2=a1;p3=a0;p4=a7;p5=a6;p6=a5;p7=a4; break;
        case 4: p0=a4;p1=a5;p2=a6;p3=a7;p4=a0;p5=a1;p6=a2;p7=a3; break;
        case 5: p0=a5;p1=a4;p2=a7;p3=a6;p4=a1;p5=a0;p6=a3;p7=a2; break;
        case 6: p0=a6;p1=a7;p2=a4;p3=a5;p4=a2;p5=a3;p6=a0;p7=a1; break;
        default:p0=a7;p1=a6;p2=a5;p3=a4;p4=a3;p5=a2;p6=a1;p7=a0; break;
        }
        const int addr = (lane ^ Mhi) << 2;  // Mhi<32 -> half-preserving
        p0.x = bperm(addr, p0.x); p0.y = bperm(addr, p0.y);
        p1.x = bperm(addr, p1.x); p1.y = bperm(addr, p1.y);
        p2.x = bperm(addr, p2.x); p2.y = bperm(addr, p2.y);
        p3.x = bperm(addr, p3.x); p3.y = bperm(addr, p3.y);
        p4.x = bperm(addr, p4.x); p4.y = bperm(addr, p4.y);
        p5.x = bperm(addr, p5.x); p5.y = bperm(addr, p5.y);
        p6.x = bperm(addr, p6.x); p6.y = bperm(addr, p6.y);
        p7.x = bperm(addr, p7.x); p7.y = bperm(addr, p7.y);
        const int pc = 7 - cq;               // control amplitude bit (uniform)
        if (pc >= 3) {
            const bool bs = (lane >> (pc - 3)) & 1;
            a0 = bs ? p0 : a0; a1 = bs ? p1 : a1; a2 = bs ? p2 : a2; a3 = bs ? p3 : a3;
            a4 = bs ? p4 : a4; a5 = bs ? p5 : a5; a6 = bs ? p6 : a6; a7 = bs ? p7 : a7;
        } else if (pc == 2) { a4 = p4; a5 = p5; a6 = p6; a7 = p7; }
        else if (pc == 1)   { a2 = p2; a3 = p3; a6 = p6; a7 = p7; }
        else                { a1 = p1; a3 = p3; a5 = p5; a7 = p7; }
    }

    // ---- conv layers; K-slot map {k0,k1,k2 | l0..l4} (R8/R9-verified) ----
    // init: {7,6,5 | 4,3,2,1,0}
    CONVM10(ws + 0);             // (6,7)
    SWKL0(0);                    // {4,6,5 | 7,3,2,1,0}
    CONVM02(ws + 16);            // (4,5)
    CONVM21(ws + 32);            // (5,6)
    SWKL2(2);                    // {4,6,2 | 7,3,5,1,0}
    SWKL1(1);                    // {4,3,2 | 7,6,5,1,0}
    CONVM21(ws + 48);            // (2,3)
    CONVM10(ws + 64);            // (3,4)
    SWKL0(3);                    // {1,3,2 | 7,6,5,4,0}
    SWKL1(4);                    // {1,0,2 | 7,6,5,4,3}
    CONVM10(ws + 80);            // (0,1)
    CONVM02(ws + 96);            // (1,2)
    // ---- layer 2 ----
    CONVM10(ws + 112);           // (0,1) + pool RY(q0) folded (hi)
    SWKL1(4);                    // {1,3,2 | 7,6,5,4,0}
    CONVM21(ws + 128);           // (2,3)
    CONVM02(ws + 144);           // (1,2) + pool RY(q2) folded (lo)
    SWKL0(3);                    // {4,3,2 | 7,6,5,1,0}
    SWKL2(2);                    // {4,3,5 | 7,6,2,1,0}
    CONVM02(ws + 160);           // (4,5)
    CONVM10(ws + 176);           // (3,4) + pool RY(q4) folded (lo)
    SWKL1(1);                    // {4,6,5 | 7,3,2,1,0}
    SWKL0(0);                    // {7,6,5 | 4,3,2,1,0}
    CONVM10(ws + 192);           // (6,7)
    CONVM21(ws + 208);           // (5,6) + pool RY(q6) folded (lo)
    // final layout: k0=q7,k1=q6,k2=q5 | l0=q4,l1=q3,l2=q2,l3=q1,l4=q0

    // ---- z: in-lane partials (q7,q6,q5) + WHT for lane qubits ----
    const float q0 = fmaf(a0.x, a0.x, a0.y * a0.y);
    const float q1 = fmaf(a1.x, a1.x, a1.y * a1.y);
    const float q2 = fmaf(a2.x, a2.x, a2.y * a2.y);
    const float q3 = fmaf(a3.x, a3.x, a3.y * a3.y);
    const float q4 = fmaf(a4.x, a4.x, a4.y * a4.y);
    const float q5 = fmaf(a5.x, a5.x, a5.y * a5.y);
    const float q6 = fmaf(a6.x, a6.x, a6.y * a6.y);
    const float q7 = fmaf(a7.x, a7.x, a7.y * a7.y);
    const float t0 = q0 + q1, t1 = q2 + q3, t2 = q4 + q5, t3 = q6 + q7;
    v2f z76;                                       // (zq7, zq6) partials
    z76.x = ((q0 - q1) + (q2 - q3)) + ((q4 - q5) + (q6 - q7));
    z76.y = (t0 - t1) + (t2 - t3);
    float z5p = (t0 + t1) - (t2 + t3);             // zq5 partial
    float w   = (t0 + t1) + (t2 + t3);             // psum -> WHT
    z76 += sx2<1>(z76);  z76 += sx2<2>(z76);  z76 += sx2<4>(z76);
    z76 += sx2<8>(z76);  z76 += sx2<16>(z76);
    z5p += sxc<1>(z5p);  z5p += sxc<2>(z5p);  z5p += sxc<4>(z5p);
    z5p += sxc<8>(z5p);  z5p += sxc<16>(z5p);
    w = whts<1>(w, lane); w = whts<2>(w, lane); w = whts<4>(w, lane);
    w = whts<8>(w, lane); w = whts<16>(w, lane);
    // lane-qubit z: q4@idx1, q3@idx2, q2@idx4, q1@idx8, q0@idx16 (per half)
    const int gb = (lane & 32) << 2;
    const float z4 = bperm(gb | (1 << 2),  w);
    const float z3 = bperm(gb | (2 << 2),  w);
    const float z2 = bperm(gb | (4 << 2),  w);
    const float z1 = bperm(gb | (8 << 2),  w);
    const float z0 = bperm(gb | (16 << 2), w);
    v4f zlo; zlo.x = z0; zlo.y = z1; zlo.z = z2;    zlo.w = z3;
    v4f zhi; zhi.x = z4; zhi.y = z5p; zhi.z = z76.y; zhi.w = z76.x;

    // ---- MLP head: 8 -> 64 (relu) -> 32 (relu) -> 1; lane = rows hl, hl+32 --
    const v4f* r0 = (const v4f*)(w1 + hl * 8);
    const v4f* r1 = (const v4f*)(w1 + (hl + 32) * 8);
    v4f ha = zlo * r0[0]; ha = __builtin_elementwise_fma(zhi, r0[1], ha);
    v4f hb = zlo * r1[0]; hb = __builtin_elementwise_fma(zhi, r1[1], hb);
    const float h1a = fmaxf(b1[hl]      + (ha.x + ha.y) + (ha.z + ha.w), 0.0f);
    const float h1b = fmaxf(b1[hl + 32] + (hb.x + hb.y) + (hb.z + hb.w), 0.0f);

    __shared__ float h1s[4][2][64];          // wave-local; no barrier needed
    h1s[wv][half][hl]      = h1a;
    h1s[wv][half][hl + 32] = h1b;

    const v4f* hv  = (const v4f*)(&h1s[wv][half][0]);
    const v4f* w2r = (const v4f*)(w2 + hl * 64);
    v4f acc = {0.0f, 0.0f, 0.0f, 0.0f};
#pragma unroll
    for (int j = 0; j < 16; j++)
        acc = __builtin_elementwise_fma(hv[j], w2r[j], acc);
    const float h2 = fmaxf(b2[hl] + (acc.x + acc.y) + (acc.z + acc.w), 0.0f);

    float o = h2 * w3[hl];
    o += sxc<1>(o); o += sxc<2>(o); o += sxc<4>(o); o += sxc<8>(o); o += sxc<16>(o);

    if (hl == 0) out[gA + half * NPAIR] = o + b3[0];
}

extern "C" void kernel_launch(void* const* d_in, const int* in_sizes, int n_in,
                              void* d_out, int out_size, void* d_ws, size_t ws_size,
                              hipStream_t stream) {
    const float* x      = (const float*)d_in[0];
    const float* adj    = (const float*)d_in[1];
    const float* w_proj = (const float*)d_in[2];
    const float* b_proj = (const float*)d_in[3];
    const float* qp     = (const float*)d_in[4];
    const float* w1     = (const float*)d_in[5];
    const float* b1     = (const float*)d_in[6];
    const float* w2     = (const float*)d_in[7];
    const float* b2     = (const float*)d_in[8];
    const float* w3     = (const float*)d_in[9];
    const float* b3     = (const float*)d_in[10];
    float* out = (float*)d_out;
    float* ws  = (float*)d_ws;                 // 224 floats

    hipLaunchKernelGGL(prep_kernel, dim3(1), dim3(64), 0, stream, qp, ws);
    hipLaunchKernelGGL(qcnn_kernel, dim3(NPAIR / 4), dim3(256), 0, stream,
                       x, adj, w_proj, b_proj, ws, w1, b1, w2, b2, w3, b3, out);
}

// Round 11
// 97.886 us; speedup vs baseline: 1.2055x; 1.0308x over previous
//
#include <hip/hip_runtime.h>
#include <math.h>

#define DEV static __device__ __forceinline__

constexpr int SS = 12;
constexpr int NN = 207;
constexpr int NCIRC = 64 * NN;          // 13248 circuits
constexpr int NPAIR = NCIRC / 2;        // 6624 waves; circuit A = lanes 0-31, B = lanes 32-63
// pair (g, g+6624): same node -> shared adjacency mask, conv matrices,
// w1/w2 rows; both circuits share ONE instruction stream.

// Layout: 32 lanes/circuit, 8 amps/lane (NAMED v2f a0..a7, re/im packed).
// Amp bits 0,1,2 = in-lane "K slots"; amp bits 3..7 = lane bits 0..4;
// lane bit 5 = circuit selector. Qubit q starts at amp bit (7-q).
//
// HARD RULE (R2/R3 LDS-demotion, R8 scratch-spill): state must be NAMED
// SCALARS; runtime permutes via wave-uniform switch over named temps.
// R11: per-circuit front-end (angles -> clip -> half-angle sincos, RZ angles)
// and the 8 adjacency masks move into an expanded prep kernel; the main
// kernel's init is 5 broadcast loads + ~40 VALU + 1 sincos.
//
// ws float layout: [0..223] 14 conv matrices (pool RYs folded, R10-verified);
// int region [224..231]: adjacency XOR masks per cq; [256 + g*24 ..]:
// per-circuit cc[8], ss[8], rz[4] (clipped ang[4..7]).

typedef float v2f __attribute__((ext_vector_type(2)));
typedef float v4f __attribute__((ext_vector_type(4)));

DEV v2f splat2(float x) { v2f r; r.x = x; r.y = x; return r; }
DEV v2f vfma(float m, v2f a, v2f acc) { return __builtin_elementwise_fma(splat2(m), a, acc); }
DEV v2f vmul(float m, v2f a) { return splat2(m) * a; }
template<int M> DEV float sxc(float v) { return __shfl_xor(v, M, 64); }
template<int M> DEV v2f sx2(v2f v) { v2f r; r.x = sxc<M>(v.x); r.y = sxc<M>(v.y); return r; }
DEV float bperm(int addr, float v) {
    return __int_as_float(__builtin_amdgcn_ds_bpermute(addr, __float_as_int(v)));
}

// real 4x4 matrix on 4 named slots (basis order b00,b01,b10,b11)
#define CONV4(P, x00, x01, x10, x11) do {                                  \
    v2f _b00 = x00, _b01 = x01, _b10 = x10, _b11 = x11;                    \
    x00 = vfma((P)[0],  _b00, vfma((P)[1],  _b01, vfma((P)[2],  _b10, vmul((P)[3],  _b11)))); \
    x01 = vfma((P)[4],  _b00, vfma((P)[5],  _b01, vfma((P)[6],  _b10, vmul((P)[7],  _b11)))); \
    x10 = vfma((P)[8],  _b00, vfma((P)[9],  _b01, vfma((P)[10], _b10, vmul((P)[11], _b11)))); \
    x11 = vfma((P)[12], _b00, vfma((P)[13], _b01, vfma((P)[14], _b10, vmul((P)[15], _b11)))); \
} while (0)

// conv on K bits; CONVM10 hi=k1,lo=k0; CONVM02 hi=k0,lo=k2; CONVM21 hi=k2,lo=k1
#define CONVM10(P) do { CONV4(P, a0, a1, a2, a3); CONV4(P, a4, a5, a6, a7); } while (0)
#define CONVM02(P) do { CONV4(P, a0, a4, a1, a5); CONV4(P, a2, a6, a3, a7); } while (0)
#define CONVM21(P) do { CONV4(P, a0, a2, a4, a6); CONV4(P, a1, a3, a5, a7); } while (0)

// half-shuffle swap of one (lo,hi) slot pair across lane bit LB
#define SWP(ML, lb, lo, hi) do {                                           \
    v2f _u = (lb) ? lo : hi;                                               \
    v2f _v = sx2<ML>(_u);                                                  \
    lo = (lb) ? _v : lo;                                                   \
    hi = (lb) ? hi : _v;                                                   \
} while (0)

#define SWKL0(LB) do { const bool _lb = (lane >> (LB)) & 1;                \
    SWP(1 << (LB), _lb, a0, a1); SWP(1 << (LB), _lb, a2, a3);              \
    SWP(1 << (LB), _lb, a4, a5); SWP(1 << (LB), _lb, a6, a7); } while (0)
#define SWKL1(LB) do { const bool _lb = (lane >> (LB)) & 1;                \
    SWP(1 << (LB), _lb, a0, a2); SWP(1 << (LB), _lb, a1, a3);              \
    SWP(1 << (LB), _lb, a4, a6); SWP(1 << (LB), _lb, a5, a7); } while (0)
#define SWKL2(LB) do { const bool _lb = (lane >> (LB)) & 1;                \
    SWP(1 << (LB), _lb, a0, a4); SWP(1 << (LB), _lb, a1, a5);              \
    SWP(1 << (LB), _lb, a2, a6); SWP(1 << (LB), _lb, a3, a7); } while (0)

// WHT butterfly stage (R7-verified)
template<int MK> DEV float whts(float p, int lane) {
    float t = sxc<MK>(p);
    return (lane & MK) ? (t - p) : (p + t);
}

// ---- prep kernel: blocks 0..51 = per-circuit front-end; block 52 = matrices
// + adjacency masks. Matrices/pool-fold code identical to R10 (verified). ----
__global__ void prep_kernel(const float* __restrict__ x, const float* __restrict__ adj,
                            const float* __restrict__ w_proj, const float* __restrict__ b_proj,
                            const float* __restrict__ qp, float* __restrict__ ws) {
    if (blockIdx.x < 52) {
        const int t = blockIdx.x * 256 + threadIdx.x;
        if (t >= NCIRC) return;
        const int b = t / NN, node = t - b * NN;
        const float* xp = x + ((size_t)b * SS * NN + node) * 2;
        v2f av0 = splat2(0.0f), av1 = av0, av2 = av0, av3 = av0,
            av4 = av0, av5 = av0, av6 = av0, av7 = av0;
#pragma unroll
        for (int s = 0; s < SS; s++) {
            const v2f xv = *(const v2f*)(xp + (size_t)s * (NN * 2));
            const float* wp = w_proj + 2 * s;
            av0 = __builtin_elementwise_fma(xv, *(const v2f*)(wp + 0 * 24), av0);
            av1 = __builtin_elementwise_fma(xv, *(const v2f*)(wp + 1 * 24), av1);
            av2 = __builtin_elementwise_fma(xv, *(const v2f*)(wp + 2 * 24), av2);
            av3 = __builtin_elementwise_fma(xv, *(const v2f*)(wp + 3 * 24), av3);
            av4 = __builtin_elementwise_fma(xv, *(const v2f*)(wp + 4 * 24), av4);
            av5 = __builtin_elementwise_fma(xv, *(const v2f*)(wp + 5 * 24), av5);
            av6 = __builtin_elementwise_fma(xv, *(const v2f*)(wp + 6 * 24), av6);
            av7 = __builtin_elementwise_fma(xv, *(const v2f*)(wp + 7 * 24), av7);
        }
        const float PI_F = 3.14159265358979323846f;
        const float ang0 = fminf(fmaxf(av0.x + av0.y + b_proj[0], -PI_F), PI_F);
        const float ang1 = fminf(fmaxf(av1.x + av1.y + b_proj[1], -PI_F), PI_F);
        const float ang2 = fminf(fmaxf(av2.x + av2.y + b_proj[2], -PI_F), PI_F);
        const float ang3 = fminf(fmaxf(av3.x + av3.y + b_proj[3], -PI_F), PI_F);
        const float ang4 = fminf(fmaxf(av4.x + av4.y + b_proj[4], -PI_F), PI_F);
        const float ang5 = fminf(fmaxf(av5.x + av5.y + b_proj[5], -PI_F), PI_F);
        const float ang6 = fminf(fmaxf(av6.x + av6.y + b_proj[6], -PI_F), PI_F);
        const float ang7 = fminf(fmaxf(av7.x + av7.y + b_proj[7], -PI_F), PI_F);
        float c0,s0,c1,s1,c2,s2,c3,s3,c4,s4,c5,s5,c6,s6,c7,s7;
        __sincosf(0.5f * ang0, &s0, &c0); __sincosf(0.5f * ang1, &s1, &c1);
        __sincosf(0.5f * ang2, &s2, &c2); __sincosf(0.5f * ang3, &s3, &c3);
        __sincosf(0.5f * ang4, &s4, &c4); __sincosf(0.5f * ang5, &s5, &c5);
        __sincosf(0.5f * ang6, &s6, &c6); __sincosf(0.5f * ang7, &s7, &c7);
        float* dst = ws + 256 + (size_t)t * 24;
        dst[0] = c0;  dst[1] = c1;  dst[2] = c2;  dst[3] = c3;
        dst[4] = c4;  dst[5] = c5;  dst[6] = c6;  dst[7] = c7;
        dst[8] = s0;  dst[9] = s1;  dst[10] = s2; dst[11] = s3;
        dst[12] = s4; dst[13] = s5; dst[14] = s6; dst[15] = s7;
        dst[16] = ang4; dst[17] = ang5; dst[18] = ang6; dst[19] = ang7;
        return;
    }
    // ---- block 52: adjacency masks + fused conv matrices ----
    const int n = threadIdx.x;
    if (n >= 14 && n < 64 + 14) {
        const int cq = n - 14;
        if (cq < 8) {
            int M = 0;
            for (int t = 0; t < 8; t++) {
                if (t != cq && adj[cq * NN + t] > 0.0f) M |= 1 << (7 - t);
            }
            ((int*)ws)[224 + cq] = M;
        }
        return;
    }
    if (n >= 14) return;
    // schedule: L1 (6,7)(4,5)(5,6)(2,3)(3,4)(0,1)(1,2); L2 (0,1)(2,3)(1,2)(4,5)(3,4)(6,7)(5,6)
    const int Jt[14] = {12, 8, 24, 4, 20, 0, 16, 28, 32, 44, 36, 48, 40, 52};
    const int J = Jt[n];
    float cg[4], sg[4];
    for (int i = 0; i < 4; i++) sincosf(0.5f * qp[J + i], &sg[i], &cg[i]);
    float A[16], B[16], M[16];
    {
        float H[2][2] = {{cg[0], -sg[0]}, {sg[0], cg[0]}};
        float L[2][2] = {{cg[1], -sg[1]}, {sg[1], cg[1]}};
        for (int a_ = 0; a_ < 2; a_++) for (int b_ = 0; b_ < 2; b_++)
            for (int p = 0; p < 2; p++) for (int q = 0; q < 2; q++)
                A[(2*a_+b_)*4 + (2*p+q)] = H[a_][p] * L[b_][q];
    }
    for (int j = 0; j < 4; j++) { float t = A[8+j]; A[8+j] = A[12+j]; A[12+j] = t; }  // CNOT hi->lo
    {
        float H[2][2] = {{cg[2], -sg[2]}, {sg[2], cg[2]}};
        float L[2][2] = {{cg[3], -sg[3]}, {sg[3], cg[3]}};
        for (int a_ = 0; a_ < 2; a_++) for (int b_ = 0; b_ < 2; b_++)
            for (int p = 0; p < 2; p++) for (int q = 0; q < 2; q++)
                B[(2*a_+b_)*4 + (2*p+q)] = H[a_][p] * L[b_][q];
    }
    for (int r = 0; r < 4; r++)
        for (int c = 0; c < 4; c++) {
            float acc = 0.0f;
            for (int k = 0; k < 4; k++) acc += B[r*4+k] * A[k*4+c];
            M[r*4+c] = acc;
        }
    for (int j = 0; j < 4; j++) { float t = M[4+j]; M[4+j] = M[12+j]; M[12+j] = t; }  // CNOT lo->hi
    // fold pool RYs (left-multiply; applied AFTER the conv) — R10-verified
    int mode = 0; float fc = 1.0f, fs = 0.0f;
    if (n == 7)  { sincosf(0.5f * qp[56], &fs, &fc); mode = 2; }   // RY(q0) on hi
    if (n == 9)  { sincosf(0.5f * qp[58], &fs, &fc); mode = 1; }   // RY(q2) on lo
    if (n == 11) { sincosf(0.5f * qp[60], &fs, &fc); mode = 1; }   // RY(q4) on lo
    if (n == 13) { sincosf(0.5f * qp[62], &fs, &fc); mode = 1; }   // RY(q6) on lo
    if (mode == 1) {
        for (int j = 0; j < 4; j++) {
            float r0 = M[j],     r1 = M[4+j];
            M[j]    = fc * r0 - fs * r1;  M[4+j]  = fs * r0 + fc * r1;
            float r2 = M[8+j],   r3 = M[12+j];
            M[8+j]  = fc * r2 - fs * r3;  M[12+j] = fs * r2 + fc * r3;
        }
    } else if (mode == 2) {
        for (int j = 0; j < 4; j++) {
            float r0 = M[j],     r2 = M[8+j];
            M[j]    = fc * r0 - fs * r2;  M[8+j]  = fs * r0 + fc * r2;
            float r1 = M[4+j],   r3 = M[12+j];
            M[4+j]  = fc * r1 - fs * r3;  M[12+j] = fs * r1 + fc * r3;
        }
    }
    for (int i = 0; i < 16; i++) ws[16*n + i] = M[i];
}

__global__ __launch_bounds__(256, 7) void qcnn_kernel(
    const float* __restrict__ ws,
    const float* __restrict__ w1, const float* __restrict__ b1,
    const float* __restrict__ w2, const float* __restrict__ b2,
    const float* __restrict__ w3, const float* __restrict__ b3,
    float* __restrict__ out)
{
    const int lane = threadIdx.x & 63;
    const int half = lane >> 5;                  // 0 = circuit A, 1 = circuit B
    const int hl   = lane & 31;
    const int wv   = threadIdx.x >> 6;
    const int gA   = blockIdx.x * 4 + wv;        // grid exact: 1656*4 == 6624
    const int bA   = gA / NN;
    const int node = gA - bA * NN;
    const int g    = gA + half * NPAIR;          // this half's circuit id

    // ---- load precomputed per-circuit trig (broadcast within each half) ----
    const float* cd = ws + 256 + (size_t)g * 24;
    const v4f cA = *(const v4f*)(cd + 0);        // c0..c3
    const v4f cB = *(const v4f*)(cd + 4);        // c4..c7
    const v4f sA = *(const v4f*)(cd + 8);        // s0..s3
    const v4f sB = *(const v4f*)(cd + 12);       // s4..s7
    const v4f rz = *(const v4f*)(cd + 16);       // clipped ang4..ang7

    // qubits 0..4 -> lane bits 4..0
    const float A = (((lane >> 4) & 1) ? sA.x : cA.x) * (((lane >> 3) & 1) ? sA.y : cA.y)
                  * (((lane >> 2) & 1) ? sA.z : cA.z) * (((lane >> 1) & 1) ? sA.w : cA.w)
                  * (((lane >> 0) & 1) ? sB.x : cB.x);
    // RZ phase: qubits 0..3 -> lane bits 4..1
    const float phi = (((lane >> 4) & 1) ? 0.5f : -0.5f) * rz.x
                    + (((lane >> 3) & 1) ? 0.5f : -0.5f) * rz.y
                    + (((lane >> 2) & 1) ? 0.5f : -0.5f) * rz.z
                    + (((lane >> 1) & 1) ? 0.5f : -0.5f) * rz.w;
    float cp, sp;
    __sincosf(phi, &sp, &cp);
    v2f ph; ph.x = cp; ph.y = sp;

    // amp bit0=q7, bit1=q6, bit2=q5
    const float c5c6 = cB.y * cB.z, c5s6 = cB.y * sB.z;
    const float s5c6 = sB.y * cB.z, s5s6 = sB.y * sB.z;
    v2f a0 = vmul(A * c5c6 * cB.w, ph), a1 = vmul(A * c5c6 * sB.w, ph);
    v2f a2 = vmul(A * c5s6 * cB.w, ph), a3 = vmul(A * c5s6 * sB.w, ph);
    v2f a4 = vmul(A * s5c6 * cB.w, ph), a5 = vmul(A * s5c6 * sB.w, ph);
    v2f a6 = vmul(A * s5s6 * cB.w, ph), a7 = vmul(A * s5s6 * sB.w, ph);

    // ---- adjacency permutation: mask precomputed in prep ----
    const int cq = node & 7;
    const int M = ((const int*)ws)[224 + cq];
    if (M) {
        const int Mlo = M & 7;               // in-lane amp bits
        const int Mhi = (M >> 3) & 31;       // lane bits (stays within half)
        v2f p0, p1, p2, p3, p4, p5, p6, p7;
        switch (Mlo) {                       // wave-uniform; p_k = a_(k^Mlo)
        case 0: p0=a0;p1=a1;p2=a2;p3=a3;p4=a4;p5=a5;p6=a6;p7=a7; break;
        case 1: p0=a1;p1=a0;p2=a3;p3=a2;p4=a5;p5=a4;p6=a7;p7=a6; break;
        case 2: p0=a2;p1=a3;p2=a0;p3=a1;p4=a6;p5=a7;p6=a4;p7=a5; break;
        case 3: p0=a3;p1=a2;p2=a1;p3=a0;p4=a7;p5=a6;p6=a5;p7=a4; break;
        case 4: p0=a4;p1=a5;p2=a6;p3=a7;p4=a0;p5=a1;p6=a2;p7=a3; break;
        case 5: p0=a5;p1=a4;p2=a7;p3=a6;p4=a1;p5=a0;p6=a3;p7=a2; break;
        case 6: p0=a6;p1=a7;p2=a4;p3=a5;p4=a2;p5=a3;p6=a0;p7=a1; break;
        default:p0=a7;p1=a6;p2=a5;p3=a4;p4=a3;p5=a2;p6=a1;p7=a0; break;
        }
        const int addr = (lane ^ Mhi) << 2;  // Mhi<32 -> half-preserving
        p0.x = bperm(addr, p0.x); p0.y = bperm(addr, p0.y);
        p1.x = bperm(addr, p1.x); p1.y = bperm(addr, p1.y);
        p2.x = bperm(addr, p2.x); p2.y = bperm(addr, p2.y);
        p3.x = bperm(addr, p3.x); p3.y = bperm(addr, p3.y);
        p4.x = bperm(addr, p4.x); p4.y = bperm(addr, p4.y);
        p5.x = bperm(addr, p5.x); p5.y = bperm(addr, p5.y);
        p6.x = bperm(addr, p6.x); p6.y = bperm(addr, p6.y);
        p7.x = bperm(addr, p7.x); p7.y = bperm(addr, p7.y);
        const int pc = 7 - cq;               // control amplitude bit (uniform)
        if (pc >= 3) {
            const bool bs = (lane >> (pc - 3)) & 1;
            a0 = bs ? p0 : a0; a1 = bs ? p1 : a1; a2 = bs ? p2 : a2; a3 = bs ? p3 : a3;
            a4 = bs ? p4 : a4; a5 = bs ? p5 : a5; a6 = bs ? p6 : a6; a7 = bs ? p7 : a7;
        } else if (pc == 2) { a4 = p4; a5 = p5; a6 = p6; a7 = p7; }
        else if (pc == 1)   { a2 = p2; a3 = p3; a6 = p6; a7 = p7; }
        else                { a1 = p1; a3 = p3; a5 = p5; a7 = p7; }
    }

    // ---- conv layers; K-slot map {k0,k1,k2 | l0..l4} (R8/R9-verified) ----
    // init: {7,6,5 | 4,3,2,1,0}
    CONVM10(ws + 0);             // (6,7)
    SWKL0(0);                    // {4,6,5 | 7,3,2,1,0}
    CONVM02(ws + 16);            // (4,5)
    CONVM21(ws + 32);            // (5,6)
    SWKL2(2);                    // {4,6,2 | 7,3,5,1,0}
    SWKL1(1);                    // {4,3,2 | 7,6,5,1,0}
    CONVM21(ws + 48);            // (2,3)
    CONVM10(ws + 64);            // (3,4)
    SWKL0(3);                    // {1,3,2 | 7,6,5,4,0}
    SWKL1(4);                    // {1,0,2 | 7,6,5,4,3}
    CONVM10(ws + 80);            // (0,1)
    CONVM02(ws + 96);            // (1,2)
    // ---- layer 2 ----
    CONVM10(ws + 112);           // (0,1) + pool RY(q0) folded (hi)
    SWKL1(4);                    // {1,3,2 | 7,6,5,4,0}
    CONVM21(ws + 128);           // (2,3)
    CONVM02(ws + 144);           // (1,2) + pool RY(q2) folded (lo)
    SWKL0(3);                    // {4,3,2 | 7,6,5,1,0}
    SWKL2(2);                    // {4,3,5 | 7,6,2,1,0}
    CONVM02(ws + 160);           // (4,5)
    CONVM10(ws + 176);           // (3,4) + pool RY(q4) folded (lo)
    SWKL1(1);                    // {4,6,5 | 7,3,2,1,0}
    SWKL0(0);                    // {7,6,5 | 4,3,2,1,0}
    CONVM10(ws + 192);           // (6,7)
    CONVM21(ws + 208);           // (5,6) + pool RY(q6) folded (lo)
    // final layout: k0=q7,k1=q6,k2=q5 | l0=q4,l1=q3,l2=q2,l3=q1,l4=q0

    // ---- z: in-lane partials (q7,q6,q5) + WHT for lane qubits ----
    const float q0 = fmaf(a0.x, a0.x, a0.y * a0.y);
    const float q1 = fmaf(a1.x, a1.x, a1.y * a1.y);
    const float q2 = fmaf(a2.x, a2.x, a2.y * a2.y);
    const float q3 = fmaf(a3.x, a3.x, a3.y * a3.y);
    const float q4 = fmaf(a4.x, a4.x, a4.y * a4.y);
    const float q5 = fmaf(a5.x, a5.x, a5.y * a5.y);
    const float q6 = fmaf(a6.x, a6.x, a6.y * a6.y);
    const float q7 = fmaf(a7.x, a7.x, a7.y * a7.y);
    const float t0 = q0 + q1, t1 = q2 + q3, t2 = q4 + q5, t3 = q6 + q7;
    v2f z76;                                       // (zq7, zq6) partials
    z76.x = ((q0 - q1) + (q2 - q3)) + ((q4 - q5) + (q6 - q7));
    z76.y = (t0 - t1) + (t2 - t3);
    float z5p = (t0 + t1) - (t2 + t3);             // zq5 partial
    float w   = (t0 + t1) + (t2 + t3);             // psum -> WHT
    z76 += sx2<1>(z76);  z76 += sx2<2>(z76);  z76 += sx2<4>(z76);
    z76 += sx2<8>(z76);  z76 += sx2<16>(z76);
    z5p += sxc<1>(z5p);  z5p += sxc<2>(z5p);  z5p += sxc<4>(z5p);
    z5p += sxc<8>(z5p);  z5p += sxc<16>(z5p);
    w = whts<1>(w, lane); w = whts<2>(w, lane); w = whts<4>(w, lane);
    w = whts<8>(w, lane); w = whts<16>(w, lane);
    // lane-qubit z: q4@idx1, q3@idx2, q2@idx4, q1@idx8, q0@idx16 (per half)
    const int gb = (lane & 32) << 2;
    const float z4 = bperm(gb | (1 << 2),  w);
    const float z3 = bperm(gb | (2 << 2),  w);
    const float z2 = bperm(gb | (4 << 2),  w);
    const float z1 = bperm(gb | (8 << 2),  w);
    const float z0 = bperm(gb | (16 << 2), w);
    v4f zlo; zlo.x = z0; zlo.y = z1;  zlo.z = z2;    zlo.w = z3;
    v4f zhi; zhi.x = z4; zhi.y = z5p; zhi.z = z76.y; zhi.w = z76.x;

    // ---- MLP head: 8 -> 64 (relu) -> 32 (relu) -> 1; lane = rows hl, hl+32 --
    const v4f* r0 = (const v4f*)(w1 + hl * 8);
    const v4f* r1 = (const v4f*)(w1 + (hl + 32) * 8);
    v4f ha = zlo * r0[0]; ha = __builtin_elementwise_fma(zhi, r0[1], ha);
    v4f hb = zlo * r1[0]; hb = __builtin_elementwise_fma(zhi, r1[1], hb);
    const float h1a = fmaxf(b1[hl]      + (ha.x + ha.y) + (ha.z + ha.w), 0.0f);
    const float h1b = fmaxf(b1[hl + 32] + (hb.x + hb.y) + (hb.z + hb.w), 0.0f);

    __shared__ float h1s[4][2][64];          // wave-local; no barrier needed
    h1s[wv][half][hl]      = h1a;
    h1s[wv][half][hl + 32] = h1b;

    const v4f* hv  = (const v4f*)(&h1s[wv][half][0]);
    const v4f* w2r = (const v4f*)(w2 + hl * 64);
    v4f acc = {0.0f, 0.0f, 0.0f, 0.0f};
#pragma unroll
    for (int j = 0; j < 16; j++)
        acc = __builtin_elementwise_fma(hv[j], w2r[j], acc);
    const float h2 = fmaxf(b2[hl] + (acc.x + acc.y) + (acc.z + acc.w), 0.0f);

    float o = h2 * w3[hl];
    o += sxc<1>(o); o += sxc<2>(o); o += sxc<4>(o); o += sxc<8>(o); o += sxc<16>(o);

    if (hl == 0) out[g] = o + b3[0];
}

extern "C" void kernel_launch(void* const* d_in, const int* in_sizes, int n_in,
                              void* d_out, int out_size, void* d_ws, size_t ws_size,
                              hipStream_t stream) {
    const float* x      = (const float*)d_in[0];
    const float* adj    = (const float*)d_in[1];
    const float* w_proj = (const float*)d_in[2];
    const float* b_proj = (const float*)d_in[3];
    const float* qp     = (const float*)d_in[4];
    const float* w1     = (const float*)d_in[5];
    const float* b1     = (const float*)d_in[6];
    const float* w2     = (const float*)d_in[7];
    const float* b2     = (const float*)d_in[8];
    const float* w3     = (const float*)d_in[9];
    const float* b3     = (const float*)d_in[10];
    float* out = (float*)d_out;
    float* ws  = (float*)d_ws;                 // 256 + 13248*24 floats ~ 1.27 MB

    hipLaunchKernelGGL(prep_kernel, dim3(53), dim3(256), 0, stream,
                       x, adj, w_proj, b_proj, qp, ws);
    hipLaunchKernelGGL(qcnn_kernel, dim3(NPAIR / 4), dim3(256), 0, stream,
                       ws, w1, b1, w2, b2, w3, b3, out);
}